// Round 11
// baseline (989.050 us; speedup 1.0000x reference)
//
#include <hip/hip_runtime.h>
#include <math.h>

#define B_   2048
#define D_   256
#define H_   8
#define DEP_ 32
#define P_   81
#define FF_  1024
#define CHW  (D_*P_)      // 20736
#define NPOS (B_*P_)      // 165888
#define KREL (D_*P_)      // 20736
#define NTOT (B_*CHW)     // 42467328
#define EPS_ 1e-5f
#define YTP  264
#define YTSZ (96*YTP)

typedef __attribute__((ext_vector_type(8))) short short8v;
typedef __attribute__((ext_vector_type(4))) short short4v;
typedef __attribute__((ext_vector_type(4))) float f32x4;

__device__ __forceinline__ float bf2f(unsigned short u){
    return __uint_as_float(((unsigned int)u) << 16);
}
__device__ __forceinline__ unsigned short f2bf(float f){
    unsigned int x = __float_as_uint(f);
    return (unsigned short)((x + 0x7FFFu + ((x >> 16) & 1u)) >> 16); // RNE
}
__device__ __forceinline__ float fast_gelu(float x){
    float u = 0.70710678118654752f * x;
    float a = fabsf(u);
    float t = __builtin_amdgcn_rcpf(fmaf(0.3275911f, a, 1.f));
    float p = t * fmaf(t, fmaf(t, fmaf(t, fmaf(t, 1.061405429f, -1.453152027f),
                         1.421413741f), -0.284496736f), 0.254829592f);
    float e = __expf(-u * u);
    float er = copysignf(fmaf(-p, e, 1.f), u);
    return 0.5f * x * (1.f + er);
}
__device__ __forceinline__ float wave16_red(float v){
    v += __shfl_xor(v, 1); v += __shfl_xor(v, 2);
    v += __shfl_xor(v, 4); v += __shfl_xor(v, 8);
    return v;
}
// C-fragment (c0: d=lh*4+r, c1: d=16+lh*4+r; col=lr) -> A/B fragment (k=lh*8+j, row/col=lr)
__device__ __forceinline__ short8v frag_redist(const f32x4 c0, const f32x4 c1, int lr, int lh){
    short8v o;
    #pragma unroll
    for (int j = 0; j < 8; ++j){
        int src = lr + 16 * (2 * (lh & 1) + (j >> 2));
        float v0 = __shfl(c0[j & 3], src);
        float v1 = __shfl(c1[j & 3], src);
        o[j] = (short)f2bf(lh < 2 ? v0 : v1);
    }
    return o;
}

// ---------------- generic f32 -> bf16 cast ----------------
__global__ __launch_bounds__(256) void k_f2bf(const float* __restrict__ w,
                                              unsigned short* __restrict__ o, int n){
    int i = blockIdx.x * 256 + threadIdx.x;
    int st = gridDim.x * 256;
    for (; i < n; i += st) o[i] = f2bf(w[i]);
}

// ---------------- K0: MFMA h-partials ----------------
__global__ __launch_bounds__(256) void k_h_mfma(const float* __restrict__ x,
                                                const unsigned short* __restrict__ w1b,
                                                float* __restrict__ ph){
    const int bt = blockIdx.x >> 2, ks = blockIdx.x & 3;
    const int t = threadIdx.x, w = t >> 6, lane = t & 63;
    const int lr = lane & 15, lh = lane >> 4;
    const int b0 = bt * 16;
    f32x4 acc0 = {0.f,0.f,0.f,0.f}, acc1 = {0.f,0.f,0.f,0.f};
    const float* xrow = x + (size_t)(b0 + lr) * KREL;
    const unsigned short* wr0 = w1b + (size_t)lr * KREL;
    const unsigned short* wr1 = w1b + (size_t)(16 + lr) * KREL;
    for (int kk = w; kk < 162; kk += 4){
        const int k0 = (ks * 162 + kk) * 32 + lh * 8;
        short8v a0 = *(const short8v*)(wr0 + k0);
        short8v a1 = *(const short8v*)(wr1 + k0);
        const float4 xv0 = *(const float4*)(xrow + k0);
        const float4 xv1 = *(const float4*)(xrow + k0 + 4);
        short8v bb;
        bb[0] = (short)f2bf(xv0.x); bb[1] = (short)f2bf(xv0.y);
        bb[2] = (short)f2bf(xv0.z); bb[3] = (short)f2bf(xv0.w);
        bb[4] = (short)f2bf(xv1.x); bb[5] = (short)f2bf(xv1.y);
        bb[6] = (short)f2bf(xv1.z); bb[7] = (short)f2bf(xv1.w);
        acc0 = __builtin_amdgcn_mfma_f32_16x16x32_bf16(a0, bb, acc0, 0, 0, 0);
        acc1 = __builtin_amdgcn_mfma_f32_16x16x32_bf16(a1, bb, acc1, 0, 0, 0);
    }
    __shared__ float red[4][32][17];
    #pragma unroll
    for (int r = 0; r < 4; ++r){
        red[w][lh * 4 + r][lr]      = acc0[r];
        red[w][16 + lh * 4 + r][lr] = acc1[r];
    }
    __syncthreads();
    for (int i = t; i < 512; i += 256){
        int j = i >> 4, bb2 = i & 15;
        float s = red[0][j][bb2] + red[1][j][bb2] + red[2][j][bb2] + red[3][j][bb2];
        ph[(size_t)ks * 65536 + (size_t)(b0 + bb2) * 32 + j] = s;
    }
}

__global__ __launch_bounds__(256) void k_h_red(const float* __restrict__ ph,
                                               float* __restrict__ h){
    int i = blockIdx.x * 256 + threadIdx.x;
    h[i] = ph[i] + ph[65536 + i] + ph[131072 + i] + ph[196608 + i];
}

// ---------------- FUSED K1 (8-wave): attention + o-proj + residual -> yT + BN1 partials ----------------
__global__ __launch_bounds__(512, 2) void k_attn_oproj8(const float* __restrict__ x,
                                                        const unsigned short* __restrict__ qkvwb,
                                                        const float* __restrict__ relw2,
                                                        const float* __restrict__ h,
                                                        const unsigned short* __restrict__ owb,
                                                        unsigned short* __restrict__ yT,
                                                        float* __restrict__ p1){
    const int b = blockIdx.x, t = threadIdx.x;
    const int lane = t & 63, w = t >> 6;
    const int lr = lane & 15, lh = lane >> 4;

    __shared__ __align__(16) unsigned short x1s[96 * 264];
    __shared__ __align__(16) unsigned short Rl[96 * 40];
    __shared__ __align__(16) unsigned short vL[8][32 * 104];
    __shared__ __align__(16) unsigned short pL[8][16 * 104];

    const float* xb = x + (size_t)b * CHW;

    {
        const float* hb = h + b * 32;
        float hreg[32];
        #pragma unroll
        for (int j = 0; j < 32; ++j) hreg[j] = hb[j];
        for (int idx = t; idx < 2592; idx += 512){
            int d = idx / 81, p = idx - d * 81;
            const float4* wr = (const float4*)(relw2 + (size_t)idx * 32);
            float s = 0.f;
            #pragma unroll
            for (int j = 0; j < 8; ++j){
                float4 wv = wr[j];
                s += wv.x * hreg[4*j] + wv.y * hreg[4*j+1] + wv.z * hreg[4*j+2] + wv.w * hreg[4*j+3];
            }
            Rl[p * 40 + d] = f2bf(s);
        }
        for (int idx = t; idx < 15 * 32; idx += 512){
            int p = 81 + (idx >> 5), d = idx & 31;
            Rl[p * 40 + d] = 0;
        }
    }
    for (int idx = t; idx < 15 * 132; idx += 512){
        int r = idx / 132, c = idx - r * 132;
        *(unsigned int*)&x1s[(81 + r) * 264 + 2 * c] = 0;
    }
    {
        float* tb = (float*)vL;
        for (int cc = 0; cc < 4; ++cc){
            for (int idx = t; idx < 64 * 81; idx += 512){
                int c = idx / 81, p = idx - c * 81;
                tb[c * 85 + p] = xb[(cc * 64 + c) * 81 + p];
            }
            __syncthreads();
            for (int idx = t; idx < 32 * 81; idx += 512){
                int c2 = idx & 31, p = idx >> 5;
                int c = 2 * c2;
                unsigned int pk = (unsigned int)f2bf(tb[c * 85 + p])
                                | ((unsigned int)f2bf(tb[(c + 1) * 85 + p]) << 16);
                *(unsigned int*)&x1s[p * 264 + cc * 64 + c] = pk;
            }
            __syncthreads();
        }
    }

    const int hh = w;
    const int qrow = hh * 32, krow = 256 + hh * 32, vrow = 512 + hh * 32;
    const int gq = (qrow / 96) * 32, gk = (krow / 96) * 32, gv = (vrow / 96) * 32;
    unsigned short* v_ = vL[w];
    unsigned short* p_ = pL[w];

    short8v bqf[6];
    {
        short8v a0 = *(const short8v*)(qkvwb + (size_t)(qrow + lr) * 32 + lh * 8);
        short8v a1 = *(const short8v*)(qkvwb + (size_t)(qrow + 16 + lr) * 32 + lh * 8);
        #pragma unroll
        for (int nt = 0; nt < 6; ++nt){
            short8v bb = *(const short8v*)(x1s + (nt * 16 + lr) * 264 + gq + lh * 8);
            f32x4 c0 = {0.f,0.f,0.f,0.f}, c1 = {0.f,0.f,0.f,0.f};
            c0 = __builtin_amdgcn_mfma_f32_16x16x32_bf16(a0, bb, c0, 0, 0, 0);
            c1 = __builtin_amdgcn_mfma_f32_16x16x32_bf16(a1, bb, c1, 0, 0, 0);
            bqf[nt] = frag_redist(c0, c1, lr, lh);
        }
    }
    short8v akf[6];
    {
        short8v a0 = *(const short8v*)(qkvwb + (size_t)(krow + lr) * 32 + lh * 8);
        short8v a1 = *(const short8v*)(qkvwb + (size_t)(krow + 16 + lr) * 32 + lh * 8);
        #pragma unroll
        for (int mt = 0; mt < 6; ++mt){
            int p = mt * 16 + lr;
            short4v r0 = *(const short4v*)(Rl + p * 40 + lh * 4);
            short4v r1 = *(const short4v*)(Rl + p * 40 + 16 + lh * 4);
            f32x4 c0, c1;
            #pragma unroll
            for (int r = 0; r < 4; ++r){
                c0[r] = bf2f((unsigned short)r0[r]);
                c1[r] = bf2f((unsigned short)r1[r]);
            }
            short8v bb = *(const short8v*)(x1s + p * 264 + gk + lh * 8);
            c0 = __builtin_amdgcn_mfma_f32_16x16x32_bf16(a0, bb, c0, 0, 0, 0);
            c1 = __builtin_amdgcn_mfma_f32_16x16x32_bf16(a1, bb, c1, 0, 0, 0);
            akf[mt] = frag_redist(c0, c1, lr, lh);
        }
    }
    {
        short8v a0 = *(const short8v*)(qkvwb + (size_t)(vrow + lr) * 32 + lh * 8);
        short8v a1 = *(const short8v*)(qkvwb + (size_t)(vrow + 16 + lr) * 32 + lh * 8);
        #pragma unroll
        for (int nt = 0; nt < 6; ++nt){
            short8v bb = *(const short8v*)(x1s + (nt * 16 + lr) * 264 + gv + lh * 8);
            f32x4 c0 = {0.f,0.f,0.f,0.f}, c1 = {0.f,0.f,0.f,0.f};
            c0 = __builtin_amdgcn_mfma_f32_16x16x32_bf16(a0, bb, c0, 0, 0, 0);
            c1 = __builtin_amdgcn_mfma_f32_16x16x32_bf16(a1, bb, c1, 0, 0, 0);
            int pk = nt * 16 + lr;
            #pragma unroll
            for (int r = 0; r < 4; ++r){
                v_[(lh * 4 + r) * 104 + pk]      = f2bf(c0[r]);
                v_[(16 + lh * 4 + r) * 104 + pk] = f2bf(c1[r]);
            }
        }
    }

    f32x4 oA[6], oB[6];
    #pragma unroll
    for (int nt = 0; nt < 6; ++nt){
        f32x4 sc[6];
        #pragma unroll
        for (int mt = 0; mt < 6; ++mt){
            f32x4 z = {0.f,0.f,0.f,0.f};
            sc[mt] = __builtin_amdgcn_mfma_f32_16x16x32_bf16(akf[mt], bqf[nt], z, 0, 0, 0);
        }
        sc[5][0] = (lh == 0) ? sc[5][0] : -1e30f;
        sc[5][1] = -1e30f; sc[5][2] = -1e30f; sc[5][3] = -1e30f;
        float mx = -1e30f;
        #pragma unroll
        for (int mt = 0; mt < 6; ++mt)
        #pragma unroll
        for (int r = 0; r < 4; ++r) mx = fmaxf(mx, sc[mt][r]);
        mx = fmaxf(mx, __shfl_xor(mx, 16));
        mx = fmaxf(mx, __shfl_xor(mx, 32));
        const float scl = 0.17677669529663687f;
        float sum = 0.f;
        #pragma unroll
        for (int mt = 0; mt < 6; ++mt)
        #pragma unroll
        for (int r = 0; r < 4; ++r){
            float e = __expf((sc[mt][r] - mx) * scl);
            sc[mt][r] = e; sum += e;
        }
        sum += __shfl_xor(sum, 16);
        sum += __shfl_xor(sum, 32);
        float inv = 1.f / sum;
        #pragma unroll
        for (int mt = 0; mt < 6; ++mt){
            short4v pv;
            #pragma unroll
            for (int r = 0; r < 4; ++r) pv[r] = (short)f2bf(sc[mt][r] * inv);
            *(short4v*)(p_ + lr * 104 + mt * 16 + lh * 4) = pv;
        }
        f32x4 o0 = {0.f,0.f,0.f,0.f}, o1 = {0.f,0.f,0.f,0.f};
        #pragma unroll
        for (int ks = 0; ks < 3; ++ks){
            short8v ap  = *(const short8v*)(p_ + lr * 104 + ks * 32 + lh * 8);
            short8v bv0 = *(const short8v*)(v_ + lr * 104 + ks * 32 + lh * 8);
            short8v bv1 = *(const short8v*)(v_ + (16 + lr) * 104 + ks * 32 + lh * 8);
            o0 = __builtin_amdgcn_mfma_f32_16x16x32_bf16(ap, bv0, o0, 0, 0, 0);
            o1 = __builtin_amdgcn_mfma_f32_16x16x32_bf16(ap, bv1, o1, 0, 0, 0);
        }
        oA[nt] = o0;
        oB[nt] = o1;
    }

    __syncthreads();
    #pragma unroll
    for (int nt = 0; nt < 6; ++nt){
        #pragma unroll
        for (int r = 0; r < 4; ++r){
            int pq = nt * 16 + lh * 4 + r;
            if (pq < 81){
                x1s[pq * 264 + hh * 32 + lr]      = f2bf(oA[nt][r]);
                x1s[pq * 264 + hh * 32 + 16 + lr] = f2bf(oB[nt][r]);
            }
        }
    }
    __syncthreads();

    const int cw = w * 32;
    f32x4 acc[2][6];
    #pragma unroll
    for (int ci = 0; ci < 2; ++ci)
    #pragma unroll
    for (int pj = 0; pj < 6; ++pj)
        acc[ci][pj] = (f32x4){0.f, 0.f, 0.f, 0.f};

    for (int ks = 0; ks < 8; ++ks){
        const int k0 = ks * 32 + lh * 8;
        short8v a[2];
        #pragma unroll
        for (int ci = 0; ci < 2; ++ci)
            a[ci] = *(const short8v*)(owb + (size_t)(cw + ci * 16 + lr) * 256 + k0);
        #pragma unroll
        for (int pj = 0; pj < 6; ++pj){
            short8v bb = *(const short8v*)(x1s + (pj * 16 + lr) * 264 + k0);
            #pragma unroll
            for (int ci = 0; ci < 2; ++ci)
                acc[ci][pj] = __builtin_amdgcn_mfma_f32_16x16x32_bf16(a[ci], bb, acc[ci][pj], 0, 0, 0);
        }
    }
    unsigned short* yb = yT + (size_t)b * YTSZ;
    float cs[8], cq[8];
    #pragma unroll
    for (int i = 0; i < 8; ++i){ cs[i] = 0.f; cq[i] = 0.f; }
    #pragma unroll
    for (int ci = 0; ci < 2; ++ci)
    #pragma unroll
    for (int pj = 0; pj < 6; ++pj){
        int p = pj * 16 + lr;
        int c = cw + ci * 16 + lh * 4;
        short4v pk;
        if (p < 81){
            #pragma unroll
            for (int r = 0; r < 4; ++r){
                float y = acc[ci][pj][r] + xb[(c + r) * 81 + p];
                pk[r] = (short)f2bf(y);
                cs[ci * 4 + r] += y;
                cq[ci * 4 + r] += y * y;
            }
        } else {
            #pragma unroll
            for (int r = 0; r < 4; ++r) pk[r] = 0;
        }
        *(short4v*)(yb + p * YTP + c) = pk;
    }
    #pragma unroll
    for (int i = 0; i < 8; ++i){
        cs[i] = wave16_red(cs[i]);
        cq[i] = wave16_red(cq[i]);
    }
    if (lr == 0){
        #pragma unroll
        for (int ci = 0; ci < 2; ++ci)
        #pragma unroll
        for (int r = 0; r < 4; ++r){
            int c = cw + ci * 16 + lh * 4 + r;
            p1[(size_t)c * 2048 + b]         = cs[ci * 4 + r];
            p1[(size_t)(256 + c) * 2048 + b] = cq[ci * 4 + r];
        }
    }
}

// ---------------- reduce partials -> (s,t) affine BN params ----------------
__global__ __launch_bounds__(256) void k_red(const float* __restrict__ part,
                                             const float* __restrict__ g, const float* __restrict__ bia,
                                             float* __restrict__ sOut, float* __restrict__ tOut){
    const int c = blockIdx.x, t = threadIdx.x;
    float s = 0.f, q = 0.f;
    #pragma unroll
    for (int i = 0; i < 8; ++i){
        s += part[(size_t)c * 2048 + t + i * 256];
        q += part[(size_t)(256 + c) * 2048 + t + i * 256];
    }
    __shared__ float rs[256], rq[256];
    rs[t] = s; rq[t] = q;
    __syncthreads();
    for (int k = 128; k; k >>= 1){
        if (t < k){ rs[t] += rs[t + k]; rq[t] += rq[t + k]; }
        __syncthreads();
    }
    if (t == 0){
        float m = rs[0] / (float)NPOS;
        float var = rq[0] / (float)NPOS - m * m;
        float sc = g[c] * rsqrtf(var + EPS_);
        sOut[c] = sc;
        tOut[c] = bia[c] - m * sc;
    }
}

// ---------------- reduce TWO partial arrays -> (s,t) ----------------
__global__ __launch_bounds__(256) void k_red2(const float* __restrict__ pa,
                                              const float* __restrict__ pb,
                                              const float* __restrict__ g, const float* __restrict__ bia,
                                              float* __restrict__ sOut, float* __restrict__ tOut){
    const int c = blockIdx.x, t = threadIdx.x;
    float s = 0.f, q = 0.f;
    #pragma unroll
    for (int i = 0; i < 8; ++i){
        size_t idx = (size_t)c * 2048 + t + i * 256;
        size_t idq = (size_t)(256 + c) * 2048 + t + i * 256;
        s += pa[idx] + pb[idx];
        q += pa[idq] + pb[idq];
    }
    __shared__ float rs[256], rq[256];
    rs[t] = s; rq[t] = q;
    __syncthreads();
    for (int k = 128; k; k >>= 1){
        if (t < k){ rs[t] += rs[t + k]; rq[t] += rq[t + k]; }
        __syncthreads();
    }
    if (t == 0){
        float m = rs[0] / (float)NPOS;
        float var = rq[0] / (float)NPOS - m * m;
        float sc = g[c] * rsqrtf(var + EPS_);
        sOut[c] = sc;
        tOut[c] = bia[c] - m * sc;
    }
}

// ---------------- w1s[f][c] = bf16(w1[f][c]*s1[c]) ----------------
__global__ __launch_bounds__(256) void k_w1scale(const float* __restrict__ w1,
                                                 const float* __restrict__ s1,
                                                 unsigned short* __restrict__ w1s){
    const int f = blockIdx.x, t = threadIdx.x;
    w1s[f * 256 + t] = f2bf(w1[f * 256 + t] * s1[t]);
}

// ---------------- bias1[f] = sum_c w1[f][c]*t1[c] ----------------
__global__ __launch_bounds__(64) void k_bias1(const float* __restrict__ w1,
                                              const float* __restrict__ t1,
                                              float* __restrict__ bias1){
    const int f = blockIdx.x, t = threadIdx.x;
    const float4 wv = *(const float4*)(w1 + f * 256 + t * 4);
    const float4 tv = *(const float4*)(t1 + t * 4);
    float s = wv.x * tv.x + wv.y * tv.y + wv.z * tv.z + wv.w * tv.w;
    #pragma unroll
    for (int m = 1; m < 64; m <<= 1) s += __shfl_xor(s, m);
    if (t == 0) bias1[f] = s;
}

// ---------------- K3 v5: 48-position blocks (4 blocks/CU), dual-stream pipelined FF ----------------
// grid = 4096: block = (batch, half). x1s[48][264]=25.3KB + ffs[2][48][72]=13.8KB -> 39.2KB.
// BN2 partials: half 0 -> p2, half 1 -> p1 (dead after k_red).
__global__ __launch_bounds__(256, 4) void k_ff_v5(unsigned short* __restrict__ yT,
                                                  const unsigned short* __restrict__ w1s,
                                                  const unsigned short* __restrict__ w2bf,
                                                  const float* __restrict__ bias1,
                                                  const float* __restrict__ s1, const float* __restrict__ t1,
                                                  float* __restrict__ p2a,
                                                  float* __restrict__ p2b){
    const int b = blockIdx.x >> 1, hhalf = blockIdx.x & 1;
    const int t = threadIdx.x;
    const int lane = t & 63, w = t >> 6;
    const int lr = lane & 15, lh = lane >> 4;

    __shared__ __align__(16) unsigned short x1s[48 * 264];    // 25344 B
    __shared__ __align__(16) unsigned short ffs[2][48 * 72];  // 13824 B

    // stage this half's 48 yT rows
    {
        const short8v* src = (const short8v*)(yT + (size_t)b * YTSZ + hhalf * 48 * YTP);
        short8v* dst = (short8v*)x1s;
        for (int idx = t; idx < 1584; idx += 256) dst[idx] = src[idx];
    }
    __syncthreads();

    const int cw = w * 64;
    const int fl = w * 16 + lh * 4;
    f32x4 acc2[4][3];
    #pragma unroll
    for (int ci = 0; ci < 4; ++ci)
    #pragma unroll
    for (int pj = 0; pj < 3; ++pj)
        acc2[ci][pj] = (f32x4){0.f, 0.f, 0.f, 0.f};

    auto g1_kloop = [&](int fc, f32x4 (&acc1)[3]){
        const int fbase = fc * 64 + w * 16;
        float b4[4];
        #pragma unroll
        for (int r = 0; r < 4; ++r) b4[r] = bias1[fbase + lh * 4 + r];
        #pragma unroll
        for (int pj = 0; pj < 3; ++pj){
            acc1[pj][0] = b4[0]; acc1[pj][1] = b4[1];
            acc1[pj][2] = b4[2]; acc1[pj][3] = b4[3];
        }
        #pragma unroll
        for (int ks = 0; ks < 8; ++ks){
            const int k0 = ks * 32 + lh * 8;
            short8v a0 = *(const short8v*)(w1s + (size_t)(fbase + lr) * 256 + k0);
            #pragma unroll
            for (int pj = 0; pj < 3; ++pj){
                short8v bb = *(const short8v*)(x1s + (pj * 16 + lr) * 264 + k0);
                acc1[pj] = __builtin_amdgcn_mfma_f32_16x16x32_bf16(a0, bb, acc1[pj], 0, 0, 0);
            }
        }
    };
    auto g2 = [&](int fc, int bf){
        #pragma unroll
        for (int ks2 = 0; ks2 < 2; ++ks2){
            const int k0 = ks2 * 32 + lh * 8;
            short8v a2[4];
            #pragma unroll
            for (int ci = 0; ci < 4; ++ci)
                a2[ci] = *(const short8v*)(w2bf + (size_t)(cw + ci * 16 + lr) * 1024 + fc * 64 + k0);
            #pragma unroll
            for (int pj = 0; pj < 3; ++pj){
                short8v bb = *(const short8v*)(ffs[bf] + (pj * 16 + lr) * 72 + k0);
                #pragma unroll
                for (int ci = 0; ci < 4; ++ci)
                    acc2[ci][pj] = __builtin_amdgcn_mfma_f32_16x16x32_bf16(a2[ci], bb, acc2[ci][pj], 0, 0, 0);
            }
        }
    };
    auto gelu_store = [&](const f32x4 (&acc1)[3], int bf){
        #pragma unroll
        for (int pj = 0; pj < 3; ++pj){
            int p = pj * 16 + lr;
            short4v pk;
            #pragma unroll
            for (int r = 0; r < 4; ++r)
                pk[r] = (short)f2bf(fast_gelu(acc1[pj][r]));
            *(short4v*)&ffs[bf][p * 72 + fl] = pk;
        }
    };

    {
        f32x4 acc1[3];
        g1_kloop(0, acc1);
        gelu_store(acc1, 0);
    }
    __syncthreads();
    for (int fc = 0; fc < 15; ++fc){
        f32x4 acc1[3];
        g1_kloop(fc + 1, acc1);
        g2(fc, fc & 1);
        gelu_store(acc1, (fc + 1) & 1);
        __syncthreads();
    }
    g2(15, 1);

    // epilogue: z = x1 + ffout; x1 = y*s1 + t1; z -> yT bf16; BN2 partials
    float sv[16], tv[16];
    #pragma unroll
    for (int ci = 0; ci < 4; ++ci)
    #pragma unroll
    for (int r = 0; r < 4; ++r){
        int c = cw + ci * 16 + lh * 4 + r;
        sv[ci * 4 + r] = s1[c];
        tv[ci * 4 + r] = t1[c];
    }
    unsigned short* zb = yT + (size_t)b * YTSZ + hhalf * 48 * YTP;
    float cs[16], cq[16];
    #pragma unroll
    for (int i = 0; i < 16; ++i){ cs[i] = 0.f; cq[i] = 0.f; }
    #pragma unroll
    for (int ci = 0; ci < 4; ++ci)
    #pragma unroll
    for (int pj = 0; pj < 3; ++pj){
        int lp = pj * 16 + lr;
        int pg = hhalf * 48 + lp;
        if (pg < 81){
            int c = cw + ci * 16 + lh * 4;
            short4v yv = *(const short4v*)&x1s[lp * 264 + c];
            short4v pk;
            #pragma unroll
            for (int r = 0; r < 4; ++r){
                float x1 = fmaf(bf2f((unsigned short)yv[r]), sv[ci * 4 + r], tv[ci * 4 + r]);
                float z = acc2[ci][pj][r] + x1;
                pk[r] = (short)f2bf(z);
                cs[ci * 4 + r] += z;
                cq[ci * 4 + r] += z * z;
            }
            *(short4v*)(zb + lp * YTP + c) = pk;
        }
    }
    #pragma unroll
    for (int i = 0; i < 16; ++i){
        cs[i] = wave16_red(cs[i]);
        cq[i] = wave16_red(cq[i]);
    }
    float* pout = hhalf ? p2b : p2a;
    if (lr == 0){
        #pragma unroll
        for (int ci = 0; ci < 4; ++ci)
        #pragma unroll
        for (int r = 0; r < 4; ++r){
            int c = cw + ci * 16 + lh * 4 + r;
            pout[(size_t)c * 2048 + b]         = cs[ci * 4 + r];
            pout[(size_t)(256 + c) * 2048 + b] = cq[ci * 4 + r];
        }
    }
}

// ---------------- BN2 apply from transposed bf16 z -> f32 out ----------------
__global__ __launch_bounds__(256) void k_bnapply_t(const unsigned short* __restrict__ yTz,
                                                   const float* __restrict__ s2, const float* __restrict__ t2,
                                                   float* __restrict__ out){
    const int b = blockIdx.x, t = threadIdx.x;
    __shared__ __align__(16) unsigned short zs[96 * 264];
    __shared__ float s2s[256], t2s[256];
    s2s[t] = s2[t];
    t2s[t] = t2[t];
    {
        const short8v* src = (const short8v*)(yTz + (size_t)b * YTSZ);
        short8v* dst = (short8v*)zs;
        for (int idx = t; idx < 3168; idx += 256) dst[idx] = src[idx];
    }
    __syncthreads();
    float* ob = out + (size_t)b * CHW;
    for (int idx = t; idx < CHW; idx += 256){
        int c = idx / 81, p = idx - c * 81;
        ob[idx] = fmaf(bf2f(zs[p * 264 + c]), s2s[c], t2s[c]);
    }
}

extern "C" void kernel_launch(void* const* d_in, const int* in_sizes, int n_in,
                              void* d_out, int out_size, void* d_ws, size_t ws_size,
                              hipStream_t stream){
    const float* x     = (const float*)d_in[0];
    const float* qkvw  = (const float*)d_in[1];
    const float* relw1 = (const float*)d_in[2];
    const float* relw2 = (const float*)d_in[3];
    const float* ow    = (const float*)d_in[4];
    const float* ffw1  = (const float*)d_in[5];
    const float* ffw2  = (const float*)d_in[6];
    const float* g1    = (const float*)d_in[7];
    const float* b1    = (const float*)d_in[8];
    const float* g2    = (const float*)d_in[9];
    const float* b2    = (const float*)d_in[10];
    float* out = (float*)d_out;
    char* ws = (char*)d_ws;

    unsigned short* w1rel = (unsigned short*)ws;             // 1,327,104 B
    float* h     = (float*)(ws + 1327104);                   // 262,144 B
    unsigned short* w2bf  = (unsigned short*)(ws + 2117632); // 524,288 B
    unsigned short* qkvwb = (unsigned short*)(ws + 2641920); // 49,152 B
    unsigned short* owb   = (unsigned short*)(ws + 2691072); // 131,072 B
    unsigned short* w1s   = (unsigned short*)(ws + 2822144); // 524,288 B
    float* bias1 = (float*)(ws + 3346432);                   // 4,096 B
    float* s1    = (float*)(ws + 3350528);
    float* t1    = (float*)(ws + 3351552);
    float* s2    = (float*)(ws + 3352576);
    float* t2    = (float*)(ws + 3353600);
    float* p1    = (float*)(ws + 3354624);                   // 4,194,304 B
    float* p2    = (float*)(ws + 7548928);                   // 4,194,304 B
    unsigned short* yT = (unsigned short*)(ws + 11743232);   // 103,809,024 B
    float* p_h = p1;

    hipLaunchKernelGGL(k_f2bf, dim3(1024), dim3(256), 0, stream, relw1, w1rel, 663552);
    hipLaunchKernelGGL(k_f2bf, dim3(256),  dim3(256), 0, stream, ffw2, w2bf, 262144);
    hipLaunchKernelGGL(k_f2bf, dim3(96),   dim3(256), 0, stream, qkvw, qkvwb, 24576);
    hipLaunchKernelGGL(k_f2bf, dim3(256),  dim3(256), 0, stream, ow, owb, 65536);

    hipLaunchKernelGGL(k_h_mfma, dim3(512), dim3(256), 0, stream, x, w1rel, p_h);
    hipLaunchKernelGGL(k_h_red,  dim3(256), dim3(256), 0, stream, p_h, h);
    hipLaunchKernelGGL(k_attn_oproj8, dim3(2048), dim3(512), 0, stream, x, qkvwb, relw2, h, owb, yT, p1);
    hipLaunchKernelGGL(k_red,      dim3(256),  dim3(256), 0, stream, p1, g1, b1, s1, t1);
    hipLaunchKernelGGL(k_w1scale,  dim3(1024), dim3(256), 0, stream, ffw1, s1, w1s);
    hipLaunchKernelGGL(k_bias1,    dim3(1024), dim3(64),  0, stream, ffw1, t1, bias1);
    hipLaunchKernelGGL(k_ff_v5,    dim3(4096), dim3(256), 0, stream, yT, w1s, w2bf, bias1, s1, t1, p2, p1);
    hipLaunchKernelGGL(k_red2,     dim3(256),  dim3(256), 0, stream, p2, p1, g2, b2, s2, t2);
    hipLaunchKernelGGL(k_bnapply_t, dim3(2048), dim3(256), 0, stream, yT, s2, t2, out);
}

// Round 12
// 793.580 us; speedup vs baseline: 1.2463x; 1.2463x over previous
//
#include <hip/hip_runtime.h>
#include <math.h>

#define B_   2048
#define D_   256
#define H_   8
#define DEP_ 32
#define P_   81
#define FF_  1024
#define CHW  (D_*P_)      // 20736
#define NPOS (B_*P_)      // 165888
#define KREL (D_*P_)      // 20736
#define NTOT (B_*CHW)     // 42467328
#define EPS_ 1e-5f
#define YTP  264
#define YTSZ (96*YTP)

typedef __attribute__((ext_vector_type(8))) short short8v;
typedef __attribute__((ext_vector_type(4))) short short4v;
typedef __attribute__((ext_vector_type(4))) float f32x4;

__device__ __forceinline__ float bf2f(unsigned short u){
    return __uint_as_float(((unsigned int)u) << 16);
}
__device__ __forceinline__ unsigned short f2bf(float f){
    unsigned int x = __float_as_uint(f);
    return (unsigned short)((x + 0x7FFFu + ((x >> 16) & 1u)) >> 16); // RNE
}
// cheap GELU: x * sigmoid(1.702 x)  (rms err ~0.008 vs exact erf-gelu)
__device__ __forceinline__ float fast_gelu(float x){
    float s = __builtin_amdgcn_rcpf(1.f + __expf(-1.702f * x));
    return x * s;
}
__device__ __forceinline__ float wave16_red(float v){
    v += __shfl_xor(v, 1); v += __shfl_xor(v, 2);
    v += __shfl_xor(v, 4); v += __shfl_xor(v, 8);
    return v;
}
// C-fragment (c0: d=lh*4+r, c1: d=16+lh*4+r; col=lr) -> A/B fragment (k=lh*8+j, row/col=lr)
__device__ __forceinline__ short8v frag_redist(const f32x4 c0, const f32x4 c1, int lr, int lh){
    short8v o;
    #pragma unroll
    for (int j = 0; j < 8; ++j){
        int src = lr + 16 * (2 * (lh & 1) + (j >> 2));
        float v0 = __shfl(c0[j & 3], src);
        float v1 = __shfl(c1[j & 3], src);
        o[j] = (short)f2bf(lh < 2 ? v0 : v1);
    }
    return o;
}

// ---------------- generic f32 -> bf16 cast ----------------
__global__ __launch_bounds__(256) void k_f2bf(const float* __restrict__ w,
                                              unsigned short* __restrict__ o, int n){
    int i = blockIdx.x * 256 + threadIdx.x;
    int st = gridDim.x * 256;
    for (; i < n; i += st) o[i] = f2bf(w[i]);
}

// ---------------- K0: MFMA h-partials ----------------
__global__ __launch_bounds__(256) void k_h_mfma(const float* __restrict__ x,
                                                const unsigned short* __restrict__ w1b,
                                                float* __restrict__ ph){
    const int bt = blockIdx.x >> 2, ks = blockIdx.x & 3;
    const int t = threadIdx.x, w = t >> 6, lane = t & 63;
    const int lr = lane & 15, lh = lane >> 4;
    const int b0 = bt * 16;
    f32x4 acc0 = {0.f,0.f,0.f,0.f}, acc1 = {0.f,0.f,0.f,0.f};
    const float* xrow = x + (size_t)(b0 + lr) * KREL;
    const unsigned short* wr0 = w1b + (size_t)lr * KREL;
    const unsigned short* wr1 = w1b + (size_t)(16 + lr) * KREL;
    for (int kk = w; kk < 162; kk += 4){
        const int k0 = (ks * 162 + kk) * 32 + lh * 8;
        short8v a0 = *(const short8v*)(wr0 + k0);
        short8v a1 = *(const short8v*)(wr1 + k0);
        const float4 xv0 = *(const float4*)(xrow + k0);
        const float4 xv1 = *(const float4*)(xrow + k0 + 4);
        short8v bb;
        bb[0] = (short)f2bf(xv0.x); bb[1] = (short)f2bf(xv0.y);
        bb[2] = (short)f2bf(xv0.z); bb[3] = (short)f2bf(xv0.w);
        bb[4] = (short)f2bf(xv1.x); bb[5] = (short)f2bf(xv1.y);
        bb[6] = (short)f2bf(xv1.z); bb[7] = (short)f2bf(xv1.w);
        acc0 = __builtin_amdgcn_mfma_f32_16x16x32_bf16(a0, bb, acc0, 0, 0, 0);
        acc1 = __builtin_amdgcn_mfma_f32_16x16x32_bf16(a1, bb, acc1, 0, 0, 0);
    }
    __shared__ float red[4][32][17];
    #pragma unroll
    for (int r = 0; r < 4; ++r){
        red[w][lh * 4 + r][lr]      = acc0[r];
        red[w][16 + lh * 4 + r][lr] = acc1[r];
    }
    __syncthreads();
    for (int i = t; i < 512; i += 256){
        int j = i >> 4, bb2 = i & 15;
        float s = red[0][j][bb2] + red[1][j][bb2] + red[2][j][bb2] + red[3][j][bb2];
        ph[(size_t)ks * 65536 + (size_t)(b0 + bb2) * 32 + j] = s;
    }
}

__global__ __launch_bounds__(256) void k_h_red(const float* __restrict__ ph,
                                               float* __restrict__ h){
    int i = blockIdx.x * 256 + threadIdx.x;
    h[i] = ph[i] + ph[65536 + i] + ph[131072 + i] + ph[196608 + i];
}

// ---------------- FUSED K1 (8-wave): attention + o-proj + residual -> yT + BN1 partials ----------------
// attT now lives in the vL/pL region (dead after PV); x1s keeps x^T bf16 so the
// residual is read from LDS instead of 48 uncoalesced f32 global loads/thread.
__global__ __launch_bounds__(512, 2) void k_attn_oproj8(const float* __restrict__ x,
                                                        const unsigned short* __restrict__ qkvwb,
                                                        const float* __restrict__ relw2,
                                                        const float* __restrict__ h,
                                                        const unsigned short* __restrict__ owb,
                                                        unsigned short* __restrict__ yT,
                                                        float* __restrict__ p1){
    const int b = blockIdx.x, t = threadIdx.x;
    const int lane = t & 63, w = t >> 6;
    const int lr = lane & 15, lh = lane >> 4;

    __shared__ __align__(16) unsigned short x1s[96 * 264];
    __shared__ __align__(16) unsigned short Rl[96 * 40];
    __shared__ __align__(16) unsigned short vL[8][32 * 104];
    __shared__ __align__(16) unsigned short pL[8][16 * 104];
    unsigned short* attT = (unsigned short*)vL;   // 25344 halfs needed, 26624 available

    const float* xb = x + (size_t)b * CHW;

    {
        const float* hb = h + b * 32;
        float hreg[32];
        #pragma unroll
        for (int j = 0; j < 32; ++j) hreg[j] = hb[j];
        for (int idx = t; idx < 2592; idx += 512){
            int d = idx / 81, p = idx - d * 81;
            const float4* wr = (const float4*)(relw2 + (size_t)idx * 32);
            float s = 0.f;
            #pragma unroll
            for (int j = 0; j < 8; ++j){
                float4 wv = wr[j];
                s += wv.x * hreg[4*j] + wv.y * hreg[4*j+1] + wv.z * hreg[4*j+2] + wv.w * hreg[4*j+3];
            }
            Rl[p * 40 + d] = f2bf(s);
        }
        for (int idx = t; idx < 15 * 32; idx += 512){
            int p = 81 + (idx >> 5), d = idx & 31;
            Rl[p * 40 + d] = 0;
        }
    }
    for (int idx = t; idx < 15 * 132; idx += 512){
        int r = idx / 132, c = idx - r * 132;
        *(unsigned int*)&x1s[(81 + r) * 264 + 2 * c] = 0;
    }
    {
        float* tb = (float*)vL;
        for (int cc = 0; cc < 4; ++cc){
            for (int idx = t; idx < 64 * 81; idx += 512){
                int c = idx / 81, p = idx - c * 81;
                tb[c * 85 + p] = xb[(cc * 64 + c) * 81 + p];
            }
            __syncthreads();
            for (int idx = t; idx < 32 * 81; idx += 512){
                int c2 = idx & 31, p = idx >> 5;
                int c = 2 * c2;
                unsigned int pk = (unsigned int)f2bf(tb[c * 85 + p])
                                | ((unsigned int)f2bf(tb[(c + 1) * 85 + p]) << 16);
                *(unsigned int*)&x1s[p * 264 + cc * 64 + c] = pk;
            }
            __syncthreads();
        }
    }

    const int hh = w;
    const int qrow = hh * 32, krow = 256 + hh * 32, vrow = 512 + hh * 32;
    const int gq = (qrow / 96) * 32, gk = (krow / 96) * 32, gv = (vrow / 96) * 32;
    unsigned short* v_ = vL[w];
    unsigned short* p_ = pL[w];

    short8v bqf[6];
    {
        short8v a0 = *(const short8v*)(qkvwb + (size_t)(qrow + lr) * 32 + lh * 8);
        short8v a1 = *(const short8v*)(qkvwb + (size_t)(qrow + 16 + lr) * 32 + lh * 8);
        #pragma unroll
        for (int nt = 0; nt < 6; ++nt){
            short8v bb = *(const short8v*)(x1s + (nt * 16 + lr) * 264 + gq + lh * 8);
            f32x4 c0 = {0.f,0.f,0.f,0.f}, c1 = {0.f,0.f,0.f,0.f};
            c0 = __builtin_amdgcn_mfma_f32_16x16x32_bf16(a0, bb, c0, 0, 0, 0);
            c1 = __builtin_amdgcn_mfma_f32_16x16x32_bf16(a1, bb, c1, 0, 0, 0);
            bqf[nt] = frag_redist(c0, c1, lr, lh);
        }
    }
    short8v akf[6];
    {
        short8v a0 = *(const short8v*)(qkvwb + (size_t)(krow + lr) * 32 + lh * 8);
        short8v a1 = *(const short8v*)(qkvwb + (size_t)(krow + 16 + lr) * 32 + lh * 8);
        #pragma unroll
        for (int mt = 0; mt < 6; ++mt){
            int p = mt * 16 + lr;
            short4v r0 = *(const short4v*)(Rl + p * 40 + lh * 4);
            short4v r1 = *(const short4v*)(Rl + p * 40 + 16 + lh * 4);
            f32x4 c0, c1;
            #pragma unroll
            for (int r = 0; r < 4; ++r){
                c0[r] = bf2f((unsigned short)r0[r]);
                c1[r] = bf2f((unsigned short)r1[r]);
            }
            short8v bb = *(const short8v*)(x1s + p * 264 + gk + lh * 8);
            c0 = __builtin_amdgcn_mfma_f32_16x16x32_bf16(a0, bb, c0, 0, 0, 0);
            c1 = __builtin_amdgcn_mfma_f32_16x16x32_bf16(a1, bb, c1, 0, 0, 0);
            akf[mt] = frag_redist(c0, c1, lr, lh);
        }
    }
    {
        short8v a0 = *(const short8v*)(qkvwb + (size_t)(vrow + lr) * 32 + lh * 8);
        short8v a1 = *(const short8v*)(qkvwb + (size_t)(vrow + 16 + lr) * 32 + lh * 8);
        #pragma unroll
        for (int nt = 0; nt < 6; ++nt){
            short8v bb = *(const short8v*)(x1s + (nt * 16 + lr) * 264 + gv + lh * 8);
            f32x4 c0 = {0.f,0.f,0.f,0.f}, c1 = {0.f,0.f,0.f,0.f};
            c0 = __builtin_amdgcn_mfma_f32_16x16x32_bf16(a0, bb, c0, 0, 0, 0);
            c1 = __builtin_amdgcn_mfma_f32_16x16x32_bf16(a1, bb, c1, 0, 0, 0);
            int pk = nt * 16 + lr;
            #pragma unroll
            for (int r = 0; r < 4; ++r){
                v_[(lh * 4 + r) * 104 + pk]      = f2bf(c0[r]);
                v_[(16 + lh * 4 + r) * 104 + pk] = f2bf(c1[r]);
            }
        }
    }

    f32x4 oA[6], oB[6];
    #pragma unroll
    for (int nt = 0; nt < 6; ++nt){
        f32x4 sc[6];
        #pragma unroll
        for (int mt = 0; mt < 6; ++mt){
            f32x4 z = {0.f,0.f,0.f,0.f};
            sc[mt] = __builtin_amdgcn_mfma_f32_16x16x32_bf16(akf[mt], bqf[nt], z, 0, 0, 0);
        }
        sc[5][0] = (lh == 0) ? sc[5][0] : -1e30f;
        sc[5][1] = -1e30f; sc[5][2] = -1e30f; sc[5][3] = -1e30f;
        float mx = -1e30f;
        #pragma unroll
        for (int mt = 0; mt < 6; ++mt)
        #pragma unroll
        for (int r = 0; r < 4; ++r) mx = fmaxf(mx, sc[mt][r]);
        mx = fmaxf(mx, __shfl_xor(mx, 16));
        mx = fmaxf(mx, __shfl_xor(mx, 32));
        const float scl = 0.17677669529663687f;
        float sum = 0.f;
        #pragma unroll
        for (int mt = 0; mt < 6; ++mt)
        #pragma unroll
        for (int r = 0; r < 4; ++r){
            float e = __expf((sc[mt][r] - mx) * scl);
            sc[mt][r] = e; sum += e;
        }
        sum += __shfl_xor(sum, 16);
        sum += __shfl_xor(sum, 32);
        float inv = 1.f / sum;
        #pragma unroll
        for (int mt = 0; mt < 6; ++mt){
            short4v pv;
            #pragma unroll
            for (int r = 0; r < 4; ++r) pv[r] = (short)f2bf(sc[mt][r] * inv);
            *(short4v*)(p_ + lr * 104 + mt * 16 + lh * 4) = pv;
        }
        f32x4 o0 = {0.f,0.f,0.f,0.f}, o1 = {0.f,0.f,0.f,0.f};
        #pragma unroll
        for (int ks = 0; ks < 3; ++ks){
            short8v ap  = *(const short8v*)(p_ + lr * 104 + ks * 32 + lh * 8);
            short8v bv0 = *(const short8v*)(v_ + lr * 104 + ks * 32 + lh * 8);
            short8v bv1 = *(const short8v*)(v_ + (16 + lr) * 104 + ks * 32 + lh * 8);
            o0 = __builtin_amdgcn_mfma_f32_16x16x32_bf16(ap, bv0, o0, 0, 0, 0);
            o1 = __builtin_amdgcn_mfma_f32_16x16x32_bf16(ap, bv1, o1, 0, 0, 0);
        }
        oA[nt] = o0;
        oB[nt] = o1;
    }

    // ---- all V/P reads done; write attT into vL region (x1s preserved)
    __syncthreads();
    #pragma unroll
    for (int nt = 0; nt < 6; ++nt){
        #pragma unroll
        for (int r = 0; r < 4; ++r){
            int pq = nt * 16 + lh * 4 + r;
            if (pq < 81){
                attT[pq * 264 + hh * 32 + lr]      = f2bf(oA[nt][r]);
                attT[pq * 264 + hh * 32 + 16 + lr] = f2bf(oB[nt][r]);
            } else {
                // zero pad rows so oproj MFMA reads are clean
                attT[pq * 264 + hh * 32 + lr]      = 0;
                attT[pq * 264 + hh * 32 + 16 + lr] = 0;
            }
        }
    }
    __syncthreads();

    const int cw = w * 32;
    f32x4 acc[2][6];
    #pragma unroll
    for (int ci = 0; ci < 2; ++ci)
    #pragma unroll
    for (int pj = 0; pj < 6; ++pj)
        acc[ci][pj] = (f32x4){0.f, 0.f, 0.f, 0.f};

    for (int ks = 0; ks < 8; ++ks){
        const int k0 = ks * 32 + lh * 8;
        short8v a[2];
        #pragma unroll
        for (int ci = 0; ci < 2; ++ci)
            a[ci] = *(const short8v*)(owb + (size_t)(cw + ci * 16 + lr) * 256 + k0);
        #pragma unroll
        for (int pj = 0; pj < 6; ++pj){
            short8v bb = *(const short8v*)(attT + (pj * 16 + lr) * 264 + k0);
            #pragma unroll
            for (int ci = 0; ci < 2; ++ci)
                acc[ci][pj] = __builtin_amdgcn_mfma_f32_16x16x32_bf16(a[ci], bb, acc[ci][pj], 0, 0, 0);
        }
    }
    unsigned short* yb = yT + (size_t)b * YTSZ;
    float cs[8], cq[8];
    #pragma unroll
    for (int i = 0; i < 8; ++i){ cs[i] = 0.f; cq[i] = 0.f; }
    #pragma unroll
    for (int ci = 0; ci < 2; ++ci)
    #pragma unroll
    for (int pj = 0; pj < 6; ++pj){
        int p = pj * 16 + lr;
        int c = cw + ci * 16 + lh * 4;
        short4v pk;
        if (p < 81){
            short4v xv = *(const short4v*)&x1s[p * 264 + c];   // residual from LDS
            #pragma unroll
            for (int r = 0; r < 4; ++r){
                float y = acc[ci][pj][r] + bf2f((unsigned short)xv[r]);
                pk[r] = (short)f2bf(y);
                cs[ci * 4 + r] += y;
                cq[ci * 4 + r] += y * y;
            }
        } else {
            #pragma unroll
            for (int r = 0; r < 4; ++r) pk[r] = 0;
        }
        *(short4v*)(yb + p * YTP + c) = pk;
    }
    #pragma unroll
    for (int i = 0; i < 8; ++i){
        cs[i] = wave16_red(cs[i]);
        cq[i] = wave16_red(cq[i]);
    }
    if (lr == 0){
        #pragma unroll
        for (int ci = 0; ci < 2; ++ci)
        #pragma unroll
        for (int r = 0; r < 4; ++r){
            int c = cw + ci * 16 + lh * 4 + r;
            p1[(size_t)c * 2048 + b]         = cs[ci * 4 + r];
            p1[(size_t)(256 + c) * 2048 + b] = cq[ci * 4 + r];
        }
    }
}

// ---------------- reduce partials -> (s,t) affine BN params ----------------
__global__ __launch_bounds__(256) void k_red(const float* __restrict__ part,
                                             const float* __restrict__ g, const float* __restrict__ bia,
                                             float* __restrict__ sOut, float* __restrict__ tOut){
    const int c = blockIdx.x, t = threadIdx.x;
    float s = 0.f, q = 0.f;
    #pragma unroll
    for (int i = 0; i < 8; ++i){
        s += part[(size_t)c * 2048 + t + i * 256];
        q += part[(size_t)(256 + c) * 2048 + t + i * 256];
    }
    __shared__ float rs[256], rq[256];
    rs[t] = s; rq[t] = q;
    __syncthreads();
    for (int k = 128; k; k >>= 1){
        if (t < k){ rs[t] += rs[t + k]; rq[t] += rq[t + k]; }
        __syncthreads();
    }
    if (t == 0){
        float m = rs[0] / (float)NPOS;
        float var = rq[0] / (float)NPOS - m * m;
        float sc = g[c] * rsqrtf(var + EPS_);
        sOut[c] = sc;
        tOut[c] = bia[c] - m * sc;
    }
}

// ---------------- w1s[f][c] = bf16(w1[f][c]*s1[c]) ----------------
__global__ __launch_bounds__(256) void k_w1scale(const float* __restrict__ w1,
                                                 const float* __restrict__ s1,
                                                 unsigned short* __restrict__ w1s){
    const int f = blockIdx.x, t = threadIdx.x;
    w1s[f * 256 + t] = f2bf(w1[f * 256 + t] * s1[t]);
}

// ---------------- bias1[f] = sum_c w1[f][c]*t1[c] ----------------
__global__ __launch_bounds__(64) void k_bias1(const float* __restrict__ w1,
                                              const float* __restrict__ t1,
                                              float* __restrict__ bias1){
    const int f = blockIdx.x, t = threadIdx.x;
    const float4 wv = *(const float4*)(w1 + f * 256 + t * 4);
    const float4 tv = *(const float4*)(t1 + t * 4);
    float s = wv.x * tv.x + wv.y * tv.y + wv.z * tv.z + wv.w * tv.w;
    #pragma unroll
    for (int m = 1; m < 64; m <<= 1) s += __shfl_xor(s, m);
    if (t == 0) bias1[f] = s;
}

// ---------------- K3 v4: dual-stream pipelined FF (cheap gelu) ----------------
__global__ __launch_bounds__(256, 2) void k_ff_v4(unsigned short* __restrict__ yT,
                                                  const unsigned short* __restrict__ w1s,
                                                  const unsigned short* __restrict__ w2bf,
                                                  const float* __restrict__ bias1,
                                                  const float* __restrict__ s1, const float* __restrict__ t1,
                                                  float* __restrict__ p2){
    const int b = blockIdx.x, t = threadIdx.x;
    const int lane = t & 63, w = t >> 6;
    const int lr = lane & 15, lh = lane >> 4;

    __shared__ __align__(16) unsigned short x1s[96 * 264];    // 50688 B (raw y bf16)
    __shared__ __align__(16) unsigned short ffs[2][96 * 72];  // 27648 B

    {
        const short8v* src = (const short8v*)(yT + (size_t)b * YTSZ);
        short8v* dst = (short8v*)x1s;
        for (int idx = t; idx < 3168; idx += 256) dst[idx] = src[idx];
    }
    __syncthreads();

    const int cw = w * 64;
    const int fl = w * 16 + lh * 4;
    f32x4 acc2[4][6];
    #pragma unroll
    for (int ci = 0; ci < 4; ++ci)
    #pragma unroll
    for (int pj = 0; pj < 6; ++pj)
        acc2[ci][pj] = (f32x4){0.f, 0.f, 0.f, 0.f};

    auto g1_kloop = [&](int fc, f32x4 (&acc1)[6]){
        const int fbase = fc * 64 + w * 16;
        float b4[4];
        #pragma unroll
        for (int r = 0; r < 4; ++r) b4[r] = bias1[fbase + lh * 4 + r];
        #pragma unroll
        for (int pj = 0; pj < 6; ++pj){
            acc1[pj][0] = b4[0]; acc1[pj][1] = b4[1];
            acc1[pj][2] = b4[2]; acc1[pj][3] = b4[3];
        }
        #pragma unroll
        for (int ks = 0; ks < 8; ++ks){
            const int k0 = ks * 32 + lh * 8;
            short8v a0 = *(const short8v*)(w1s + (size_t)(fbase + lr) * 256 + k0);
            #pragma unroll
            for (int pj = 0; pj < 6; ++pj){
                short8v bb = *(const short8v*)(x1s + (pj * 16 + lr) * 264 + k0);
                acc1[pj] = __builtin_amdgcn_mfma_f32_16x16x32_bf16(a0, bb, acc1[pj], 0, 0, 0);
            }
        }
    };
    auto g2 = [&](int fc, int bf){
        #pragma unroll
        for (int ks2 = 0; ks2 < 2; ++ks2){
            const int k0 = ks2 * 32 + lh * 8;
            short8v a2[4];
            #pragma unroll
            for (int ci = 0; ci < 4; ++ci)
                a2[ci] = *(const short8v*)(w2bf + (size_t)(cw + ci * 16 + lr) * 1024 + fc * 64 + k0);
            #pragma unroll
            for (int pj = 0; pj < 6; ++pj){
                short8v bb = *(const short8v*)(ffs[bf] + (pj * 16 + lr) * 72 + k0);
                #pragma unroll
                for (int ci = 0; ci < 4; ++ci)
                    acc2[ci][pj] = __builtin_amdgcn_mfma_f32_16x16x32_bf16(a2[ci], bb, acc2[ci][pj], 0, 0, 0);
            }
        }
    };
    auto gelu_store = [&](const f32x4 (&acc1)[6], int bf){
        #pragma unroll
        for (int pj = 0; pj < 6; ++pj){
            int p = pj * 16 + lr;
            short4v pk;
            #pragma unroll
            for (int r = 0; r < 4; ++r)
                pk[r] = (short)f2bf(fast_gelu(acc1[pj][r]));
            *(short4v*)&ffs[bf][p * 72 + fl] = pk;
        }
    };

    {
        f32x4 acc1[6];
        g1_kloop(0, acc1);
        gelu_store(acc1, 0);
    }
    __syncthreads();
    for (int fc = 0; fc < 15; ++fc){
        f32x4 acc1[6];
        g1_kloop(fc + 1, acc1);
        g2(fc, fc & 1);
        gelu_store(acc1, (fc + 1) & 1);
        __syncthreads();
    }
    g2(15, 1);

    float sv[16], tv[16];
    #pragma unroll
    for (int ci = 0; ci < 4; ++ci)
    #pragma unroll
    for (int r = 0; r < 4; ++r){
        int c = cw + ci * 16 + lh * 4 + r;
        sv[ci * 4 + r] = s1[c];
        tv[ci * 4 + r] = t1[c];
    }
    unsigned short* zb = yT + (size_t)b * YTSZ;
    float cs[16], cq[16];
    #pragma unroll
    for (int i = 0; i < 16; ++i){ cs[i] = 0.f; cq[i] = 0.f; }
    #pragma unroll
    for (int ci = 0; ci < 4; ++ci)
    #pragma unroll
    for (int pj = 0; pj < 6; ++pj){
        int p = pj * 16 + lr;
        if (p < 81){
            int c = cw + ci * 16 + lh * 4;
            short4v yv = *(const short4v*)&x1s[p * 264 + c];
            short4v pk;
            #pragma unroll
            for (int r = 0; r < 4; ++r){
                float x1 = fmaf(bf2f((unsigned short)yv[r]), sv[ci * 4 + r], tv[ci * 4 + r]);
                float z = acc2[ci][pj][r] + x1;
                pk[r] = (short)f2bf(z);
                cs[ci * 4 + r] += z;
                cq[ci * 4 + r] += z * z;
            }
            *(short4v*)(zb + p * YTP + c) = pk;
        }
    }
    #pragma unroll
    for (int i = 0; i < 16; ++i){
        cs[i] = wave16_red(cs[i]);
        cq[i] = wave16_red(cq[i]);
    }
    if (lr == 0){
        #pragma unroll
        for (int ci = 0; ci < 4; ++ci)
        #pragma unroll
        for (int r = 0; r < 4; ++r){
            int c = cw + ci * 16 + lh * 4 + r;
            p2[(size_t)c * 2048 + b]         = cs[ci * 4 + r];
            p2[(size_t)(256 + c) * 2048 + b] = cq[ci * 4 + r];
        }
    }
}

// ---------------- BN2 apply from transposed bf16 z -> f32 out ----------------
__global__ __launch_bounds__(256) void k_bnapply_t(const unsigned short* __restrict__ yTz,
                                                   const float* __restrict__ s2, const float* __restrict__ t2,
                                                   float* __restrict__ out){
    const int b = blockIdx.x, t = threadIdx.x;
    __shared__ __align__(16) unsigned short zs[96 * 264];
    __shared__ float s2s[256], t2s[256];
    s2s[t] = s2[t];
    t2s[t] = t2[t];
    {
        const short8v* src = (const short8v*)(yTz + (size_t)b * YTSZ);
        short8v* dst = (short8v*)zs;
        for (int idx = t; idx < 3168; idx += 256) dst[idx] = src[idx];
    }
    __syncthreads();
    float* ob = out + (size_t)b * CHW;
    for (int idx = t; idx < CHW; idx += 256){
        int c = idx / 81, p = idx - c * 81;
        ob[idx] = fmaf(bf2f(zs[p * 264 + c]), s2s[c], t2s[c]);
    }
}

extern "C" void kernel_launch(void* const* d_in, const int* in_sizes, int n_in,
                              void* d_out, int out_size, void* d_ws, size_t ws_size,
                              hipStream_t stream){
    const float* x     = (const float*)d_in[0];
    const float* qkvw  = (const float*)d_in[1];
    const float* relw1 = (const float*)d_in[2];
    const float* relw2 = (const float*)d_in[3];
    const float* ow    = (const float*)d_in[4];
    const float* ffw1  = (const float*)d_in[5];
    const float* ffw2  = (const float*)d_in[6];
    const float* g1    = (const float*)d_in[7];
    const float* b1    = (const float*)d_in[8];
    const float* g2    = (const float*)d_in[9];
    const float* b2    = (const float*)d_in[10];
    float* out = (float*)d_out;
    char* ws = (char*)d_ws;

    unsigned short* w1rel = (unsigned short*)ws;             // 1,327,104 B
    float* h     = (float*)(ws + 1327104);                   // 262,144 B
    unsigned short* w2bf  = (unsigned short*)(ws + 2117632); // 524,288 B
    unsigned short* qkvwb = (unsigned short*)(ws + 2641920); // 49,152 B
    unsigned short* owb   = (unsigned short*)(ws + 2691072); // 131,072 B
    unsigned short* w1s   = (unsigned short*)(ws + 2822144); // 524,288 B
    float* bias1 = (float*)(ws + 3346432);                   // 4,096 B
    float* s1    = (float*)(ws + 3350528);
    float* t1    = (float*)(ws + 3351552);
    float* s2    = (float*)(ws + 3352576);
    float* t2    = (float*)(ws + 3353600);
    float* p1    = (float*)(ws + 3354624);                   // 4,194,304 B
    float* p2    = (float*)(ws + 7548928);                   // 4,194,304 B
    unsigned short* yT = (unsigned short*)(ws + 11743232);   // 103,809,024 B
    float* p_h = p1;

    hipLaunchKernelGGL(k_f2bf, dim3(1024), dim3(256), 0, stream, relw1, w1rel, 663552);
    hipLaunchKernelGGL(k_f2bf, dim3(256),  dim3(256), 0, stream, ffw2, w2bf, 262144);
    hipLaunchKernelGGL(k_f2bf, dim3(96),   dim3(256), 0, stream, qkvw, qkvwb, 24576);
    hipLaunchKernelGGL(k_f2bf, dim3(256),  dim3(256), 0, stream, ow, owb, 65536);

    hipLaunchKernelGGL(k_h_mfma, dim3(512), dim3(256), 0, stream, x, w1rel, p_h);
    hipLaunchKernelGGL(k_h_red,  dim3(256), dim3(256), 0, stream, p_h, h);
    hipLaunchKernelGGL(k_attn_oproj8, dim3(2048), dim3(512), 0, stream, x, qkvwb, relw2, h, owb, yT, p1);
    hipLaunchKernelGGL(k_red,      dim3(256),  dim3(256), 0, stream, p1, g1, b1, s1, t1);
    hipLaunchKernelGGL(k_w1scale,  dim3(1024), dim3(256), 0, stream, ffw1, s1, w1s);
    hipLaunchKernelGGL(k_bias1,    dim3(1024), dim3(64),  0, stream, ffw1, t1, bias1);
    hipLaunchKernelGGL(k_ff_v4,    dim3(2048), dim3(256), 0, stream, yT, w1s, w2bf, bias1, s1, t1, p2);
    hipLaunchKernelGGL(k_red,      dim3(256),  dim3(256), 0, stream, p2, g2, b2, s2, t2);
    hipLaunchKernelGGL(k_bnapply_t, dim3(2048), dim3(256), 0, stream, yT, s2, t2, out);
}

// Round 13
// 690.777 us; speedup vs baseline: 1.4318x; 1.1488x over previous
//
#include <hip/hip_runtime.h>
#include <math.h>

#define B_   2048
#define D_   256
#define H_   8
#define DEP_ 32
#define P_   81
#define FF_  1024
#define CHW  (D_*P_)      // 20736
#define NPOS (B_*P_)      // 165888
#define KREL (D_*P_)      // 20736
#define NTOT (B_*CHW)     // 42467328
#define EPS_ 1e-5f
#define YTP  264
#define YTSZ (96*YTP)

typedef __attribute__((ext_vector_type(8))) short short8v;
typedef __attribute__((ext_vector_type(4))) short short4v;
typedef __attribute__((ext_vector_type(4))) float f32x4;

__device__ __forceinline__ float bf2f(unsigned short u){
    return __uint_as_float(((unsigned int)u) << 16);
}
__device__ __forceinline__ unsigned short f2bf(float f){
    unsigned int x = __float_as_uint(f);
    return (unsigned short)((x + 0x7FFFu + ((x >> 16) & 1u)) >> 16); // RNE
}
// cheap GELU: x * sigmoid(1.702 x)
__device__ __forceinline__ float fast_gelu(float x){
    float s = __builtin_amdgcn_rcpf(1.f + __expf(-1.702f * x));
    return x * s;
}
__device__ __forceinline__ float wave16_red(float v){
    v += __shfl_xor(v, 1); v += __shfl_xor(v, 2);
    v += __shfl_xor(v, 4); v += __shfl_xor(v, 8);
    return v;
}
// C-fragment (c0: d=lh*4+r, c1: d=16+lh*4+r; col=lr) -> A/B fragment (k=lh*8+j, row/col=lr)
__device__ __forceinline__ short8v frag_redist(const f32x4 c0, const f32x4 c1, int lr, int lh){
    short8v o;
    #pragma unroll
    for (int j = 0; j < 8; ++j){
        int src = lr + 16 * (2 * (lh & 1) + (j >> 2));
        float v0 = __shfl(c0[j & 3], src);
        float v1 = __shfl(c1[j & 3], src);
        o[j] = (short)f2bf(lh < 2 ? v0 : v1);
    }
    return o;
}

// ---------------- K00: all weight casts in one kernel ----------------
__global__ __launch_bounds__(256) void k_prep(const float* __restrict__ relw1,
                                              const float* __restrict__ ffw2,
                                              const float* __restrict__ qkvw,
                                              const float* __restrict__ ow,
                                              unsigned short* __restrict__ w1rel,
                                              unsigned short* __restrict__ w2bf,
                                              unsigned short* __restrict__ qkvwb,
                                              unsigned short* __restrict__ owb){
    int i = blockIdx.x * 256 + threadIdx.x;
    int st = gridDim.x * 256;
    for (; i < 1015808; i += st){
        if (i < 663552)                w1rel[i]           = f2bf(relw1[i]);
        else if (i < 925696)           w2bf[i - 663552]   = f2bf(ffw2[i - 663552]);
        else if (i < 950272)           qkvwb[i - 925696]  = f2bf(qkvw[i - 925696]);
        else                           owb[i - 950272]    = f2bf(ow[i - 950272]);
    }
}

// ---------------- K0: MFMA h-partials ----------------
__global__ __launch_bounds__(256) void k_h_mfma(const float* __restrict__ x,
                                                const unsigned short* __restrict__ w1b,
                                                float* __restrict__ ph){
    const int bt = blockIdx.x >> 2, ks = blockIdx.x & 3;
    const int t = threadIdx.x, w = t >> 6, lane = t & 63;
    const int lr = lane & 15, lh = lane >> 4;
    const int b0 = bt * 16;
    f32x4 acc0 = {0.f,0.f,0.f,0.f}, acc1 = {0.f,0.f,0.f,0.f};
    const float* xrow = x + (size_t)(b0 + lr) * KREL;
    const unsigned short* wr0 = w1b + (size_t)lr * KREL;
    const unsigned short* wr1 = w1b + (size_t)(16 + lr) * KREL;
    for (int kk = w; kk < 162; kk += 4){
        const int k0 = (ks * 162 + kk) * 32 + lh * 8;
        short8v a0 = *(const short8v*)(wr0 + k0);
        short8v a1 = *(const short8v*)(wr1 + k0);
        const float4 xv0 = *(const float4*)(xrow + k0);
        const float4 xv1 = *(const float4*)(xrow + k0 + 4);
        short8v bb;
        bb[0] = (short)f2bf(xv0.x); bb[1] = (short)f2bf(xv0.y);
        bb[2] = (short)f2bf(xv0.z); bb[3] = (short)f2bf(xv0.w);
        bb[4] = (short)f2bf(xv1.x); bb[5] = (short)f2bf(xv1.y);
        bb[6] = (short)f2bf(xv1.z); bb[7] = (short)f2bf(xv1.w);
        acc0 = __builtin_amdgcn_mfma_f32_16x16x32_bf16(a0, bb, acc0, 0, 0, 0);
        acc1 = __builtin_amdgcn_mfma_f32_16x16x32_bf16(a1, bb, acc1, 0, 0, 0);
    }
    __shared__ float red[4][32][17];
    #pragma unroll
    for (int r = 0; r < 4; ++r){
        red[w][lh * 4 + r][lr]      = acc0[r];
        red[w][16 + lh * 4 + r][lr] = acc1[r];
    }
    __syncthreads();
    for (int i = t; i < 512; i += 256){
        int j = i >> 4, bb2 = i & 15;
        float s = red[0][j][bb2] + red[1][j][bb2] + red[2][j][bb2] + red[3][j][bb2];
        ph[(size_t)ks * 65536 + (size_t)(b0 + bb2) * 32 + j] = s;
    }
}

__global__ __launch_bounds__(256) void k_h_red(const float* __restrict__ ph,
                                               float* __restrict__ h){
    int i = blockIdx.x * 256 + threadIdx.x;
    h[i] = ph[i] + ph[65536 + i] + ph[131072 + i] + ph[196608 + i];
}

// ---------------- FUSED K1 (8-wave): attention + o-proj + residual -> yT + BN1 partials ----------------
__global__ __launch_bounds__(512, 2) void k_attn_oproj8(const float* __restrict__ x,
                                                        const unsigned short* __restrict__ qkvwb,
                                                        const float* __restrict__ relw2,
                                                        const float* __restrict__ h,
                                                        const unsigned short* __restrict__ owb,
                                                        unsigned short* __restrict__ yT,
                                                        float* __restrict__ p1){
    const int b = blockIdx.x, t = threadIdx.x;
    const int lane = t & 63, w = t >> 6;
    const int lr = lane & 15, lh = lane >> 4;

    __shared__ __align__(16) unsigned short x1s[96 * 264];
    __shared__ __align__(16) unsigned short Rl[96 * 40];
    __shared__ __align__(16) unsigned short vL[8][32 * 104];
    __shared__ __align__(16) unsigned short pL[8][16 * 104];
    unsigned short* attT = (unsigned short*)vL;

    const float* xb = x + (size_t)b * CHW;

    {
        const float* hb = h + b * 32;
        float hreg[32];
        #pragma unroll
        for (int j = 0; j < 32; ++j) hreg[j] = hb[j];
        for (int idx = t; idx < 2592; idx += 512){
            int d = idx / 81, p = idx - d * 81;
            const float4* wr = (const float4*)(relw2 + (size_t)idx * 32);
            float s = 0.f;
            #pragma unroll
            for (int j = 0; j < 8; ++j){
                float4 wv = wr[j];
                s += wv.x * hreg[4*j] + wv.y * hreg[4*j+1] + wv.z * hreg[4*j+2] + wv.w * hreg[4*j+3];
            }
            Rl[p * 40 + d] = f2bf(s);
        }
        for (int idx = t; idx < 15 * 32; idx += 512){
            int p = 81 + (idx >> 5), d = idx & 31;
            Rl[p * 40 + d] = 0;
        }
    }
    // zero x1s pad rows
    for (int idx = t; idx < 15 * 132; idx += 512){
        int r = idx / 132, c = idx - r * 132;
        *(unsigned int*)&x1s[(81 + r) * 264 + 2 * c] = 0;
    }
    // direct-pack staging: x[c][p] f32 -> x1s[p][c] bf16 (no bounce, 1 barrier)
    for (int idx = t; idx < 81 * 128; idx += 512){
        int c2 = idx / 81, p = idx - c2 * 81;
        int c = 2 * c2;
        unsigned int pk = (unsigned int)f2bf(xb[c * 81 + p])
                        | ((unsigned int)f2bf(xb[(c + 1) * 81 + p]) << 16);
        *(unsigned int*)&x1s[p * 264 + c] = pk;
    }
    __syncthreads();

    const int hh = w;
    const int qrow = hh * 32, krow = 256 + hh * 32, vrow = 512 + hh * 32;
    const int gq = (qrow / 96) * 32, gk = (krow / 96) * 32, gv = (vrow / 96) * 32;
    unsigned short* v_ = vL[w];
    unsigned short* p_ = pL[w];

    __builtin_amdgcn_s_setprio(1);
    short8v bqf[6];
    {
        short8v a0 = *(const short8v*)(qkvwb + (size_t)(qrow + lr) * 32 + lh * 8);
        short8v a1 = *(const short8v*)(qkvwb + (size_t)(qrow + 16 + lr) * 32 + lh * 8);
        #pragma unroll
        for (int nt = 0; nt < 6; ++nt){
            short8v bb = *(const short8v*)(x1s + (nt * 16 + lr) * 264 + gq + lh * 8);
            f32x4 c0 = {0.f,0.f,0.f,0.f}, c1 = {0.f,0.f,0.f,0.f};
            c0 = __builtin_amdgcn_mfma_f32_16x16x32_bf16(a0, bb, c0, 0, 0, 0);
            c1 = __builtin_amdgcn_mfma_f32_16x16x32_bf16(a1, bb, c1, 0, 0, 0);
            bqf[nt] = frag_redist(c0, c1, lr, lh);
        }
    }
    short8v akf[6];
    {
        short8v a0 = *(const short8v*)(qkvwb + (size_t)(krow + lr) * 32 + lh * 8);
        short8v a1 = *(const short8v*)(qkvwb + (size_t)(krow + 16 + lr) * 32 + lh * 8);
        #pragma unroll
        for (int mt = 0; mt < 6; ++mt){
            int p = mt * 16 + lr;
            short4v r0 = *(const short4v*)(Rl + p * 40 + lh * 4);
            short4v r1 = *(const short4v*)(Rl + p * 40 + 16 + lh * 4);
            f32x4 c0, c1;
            #pragma unroll
            for (int r = 0; r < 4; ++r){
                c0[r] = bf2f((unsigned short)r0[r]);
                c1[r] = bf2f((unsigned short)r1[r]);
            }
            short8v bb = *(const short8v*)(x1s + p * 264 + gk + lh * 8);
            c0 = __builtin_amdgcn_mfma_f32_16x16x32_bf16(a0, bb, c0, 0, 0, 0);
            c1 = __builtin_amdgcn_mfma_f32_16x16x32_bf16(a1, bb, c1, 0, 0, 0);
            akf[mt] = frag_redist(c0, c1, lr, lh);
        }
    }
    {
        short8v a0 = *(const short8v*)(qkvwb + (size_t)(vrow + lr) * 32 + lh * 8);
        short8v a1 = *(const short8v*)(qkvwb + (size_t)(vrow + 16 + lr) * 32 + lh * 8);
        #pragma unroll
        for (int nt = 0; nt < 6; ++nt){
            short8v bb = *(const short8v*)(x1s + (nt * 16 + lr) * 264 + gv + lh * 8);
            f32x4 c0 = {0.f,0.f,0.f,0.f}, c1 = {0.f,0.f,0.f,0.f};
            c0 = __builtin_amdgcn_mfma_f32_16x16x32_bf16(a0, bb, c0, 0, 0, 0);
            c1 = __builtin_amdgcn_mfma_f32_16x16x32_bf16(a1, bb, c1, 0, 0, 0);
            int pk = nt * 16 + lr;
            #pragma unroll
            for (int r = 0; r < 4; ++r){
                v_[(lh * 4 + r) * 104 + pk]      = f2bf(c0[r]);
                v_[(16 + lh * 4 + r) * 104 + pk] = f2bf(c1[r]);
            }
        }
    }

    f32x4 oA[6], oB[6];
    #pragma unroll
    for (int nt = 0; nt < 6; ++nt){
        f32x4 sc[6];
        #pragma unroll
        for (int mt = 0; mt < 6; ++mt){
            f32x4 z = {0.f,0.f,0.f,0.f};
            sc[mt] = __builtin_amdgcn_mfma_f32_16x16x32_bf16(akf[mt], bqf[nt], z, 0, 0, 0);
        }
        sc[5][0] = (lh == 0) ? sc[5][0] : -1e30f;
        sc[5][1] = -1e30f; sc[5][2] = -1e30f; sc[5][3] = -1e30f;
        float mx = -1e30f;
        #pragma unroll
        for (int mt = 0; mt < 6; ++mt)
        #pragma unroll
        for (int r = 0; r < 4; ++r) mx = fmaxf(mx, sc[mt][r]);
        mx = fmaxf(mx, __shfl_xor(mx, 16));
        mx = fmaxf(mx, __shfl_xor(mx, 32));
        const float scl = 0.17677669529663687f;
        float sum = 0.f;
        #pragma unroll
        for (int mt = 0; mt < 6; ++mt)
        #pragma unroll
        for (int r = 0; r < 4; ++r){
            float e = __expf((sc[mt][r] - mx) * scl);
            sc[mt][r] = e; sum += e;
        }
        sum += __shfl_xor(sum, 16);
        sum += __shfl_xor(sum, 32);
        float inv = 1.f / sum;
        #pragma unroll
        for (int mt = 0; mt < 6; ++mt){
            short4v pv;
            #pragma unroll
            for (int r = 0; r < 4; ++r) pv[r] = (short)f2bf(sc[mt][r] * inv);
            *(short4v*)(p_ + lr * 104 + mt * 16 + lh * 4) = pv;
        }
        f32x4 o0 = {0.f,0.f,0.f,0.f}, o1 = {0.f,0.f,0.f,0.f};
        #pragma unroll
        for (int ks = 0; ks < 3; ++ks){
            short8v ap  = *(const short8v*)(p_ + lr * 104 + ks * 32 + lh * 8);
            short8v bv0 = *(const short8v*)(v_ + lr * 104 + ks * 32 + lh * 8);
            short8v bv1 = *(const short8v*)(v_ + (16 + lr) * 104 + ks * 32 + lh * 8);
            o0 = __builtin_amdgcn_mfma_f32_16x16x32_bf16(ap, bv0, o0, 0, 0, 0);
            o1 = __builtin_amdgcn_mfma_f32_16x16x32_bf16(ap, bv1, o1, 0, 0, 0);
        }
        oA[nt] = o0;
        oB[nt] = o1;
    }
    __builtin_amdgcn_s_setprio(0);

    // ---- all V/P reads done; write attT into vL region (x1s preserved)
    __syncthreads();
    #pragma unroll
    for (int nt = 0; nt < 6; ++nt){
        #pragma unroll
        for (int r = 0; r < 4; ++r){
            int pq = nt * 16 + lh * 4 + r;
            if (pq < 81){
                attT[pq * 264 + hh * 32 + lr]      = f2bf(oA[nt][r]);
                attT[pq * 264 + hh * 32 + 16 + lr] = f2bf(oB[nt][r]);
            } else {
                attT[pq * 264 + hh * 32 + lr]      = 0;
                attT[pq * 264 + hh * 32 + 16 + lr] = 0;
            }
        }
    }
    __syncthreads();

    const int cw = w * 32;
    f32x4 acc[2][6];
    #pragma unroll
    for (int ci = 0; ci < 2; ++ci)
    #pragma unroll
    for (int pj = 0; pj < 6; ++pj)
        acc[ci][pj] = (f32x4){0.f, 0.f, 0.f, 0.f};

    __builtin_amdgcn_s_setprio(1);
    for (int ks = 0; ks < 8; ++ks){
        const int k0 = ks * 32 + lh * 8;
        short8v a[2];
        #pragma unroll
        for (int ci = 0; ci < 2; ++ci)
            a[ci] = *(const short8v*)(owb + (size_t)(cw + ci * 16 + lr) * 256 + k0);
        #pragma unroll
        for (int pj = 0; pj < 6; ++pj){
            short8v bb = *(const short8v*)(attT + (pj * 16 + lr) * 264 + k0);
            #pragma unroll
            for (int ci = 0; ci < 2; ++ci)
                acc[ci][pj] = __builtin_amdgcn_mfma_f32_16x16x32_bf16(a[ci], bb, acc[ci][pj], 0, 0, 0);
        }
    }
    __builtin_amdgcn_s_setprio(0);
    unsigned short* yb = yT + (size_t)b * YTSZ;
    float cs[8], cq[8];
    #pragma unroll
    for (int i = 0; i < 8; ++i){ cs[i] = 0.f; cq[i] = 0.f; }
    #pragma unroll
    for (int ci = 0; ci < 2; ++ci)
    #pragma unroll
    for (int pj = 0; pj < 6; ++pj){
        int p = pj * 16 + lr;
        int c = cw + ci * 16 + lh * 4;
        short4v pk;
        if (p < 81){
            short4v xv = *(const short4v*)&x1s[p * 264 + c];
            #pragma unroll
            for (int r = 0; r < 4; ++r){
                float y = acc[ci][pj][r] + bf2f((unsigned short)xv[r]);
                pk[r] = (short)f2bf(y);
                cs[ci * 4 + r] += y;
                cq[ci * 4 + r] += y * y;
            }
        } else {
            #pragma unroll
            for (int r = 0; r < 4; ++r) pk[r] = 0;
        }
        *(short4v*)(yb + p * YTP + c) = pk;
    }
    #pragma unroll
    for (int i = 0; i < 8; ++i){
        cs[i] = wave16_red(cs[i]);
        cq[i] = wave16_red(cq[i]);
    }
    if (lr == 0){
        #pragma unroll
        for (int ci = 0; ci < 2; ++ci)
        #pragma unroll
        for (int r = 0; r < 4; ++r){
            int c = cw + ci * 16 + lh * 4 + r;
            p1[(size_t)c * 2048 + b]         = cs[ci * 4 + r];
            p1[(size_t)(256 + c) * 2048 + b] = cq[ci * 4 + r];
        }
    }
}

// ---------------- reduce partials -> (s,t) affine BN params ----------------
__global__ __launch_bounds__(256) void k_red(const float* __restrict__ part,
                                             const float* __restrict__ g, const float* __restrict__ bia,
                                             float* __restrict__ sOut, float* __restrict__ tOut){
    const int c = blockIdx.x, t = threadIdx.x;
    float s = 0.f, q = 0.f;
    #pragma unroll
    for (int i = 0; i < 8; ++i){
        s += part[(size_t)c * 2048 + t + i * 256];
        q += part[(size_t)(256 + c) * 2048 + t + i * 256];
    }
    __shared__ float rs[256], rq[256];
    rs[t] = s; rq[t] = q;
    __syncthreads();
    for (int k = 128; k; k >>= 1){
        if (t < k){ rs[t] += rs[t + k]; rq[t] += rq[t + k]; }
        __syncthreads();
    }
    if (t == 0){
        float m = rs[0] / (float)NPOS;
        float var = rq[0] / (float)NPOS - m * m;
        float sc = g[c] * rsqrtf(var + EPS_);
        sOut[c] = sc;
        tOut[c] = bia[c] - m * sc;
    }
}

// ---------------- fused: w1s[f][:] = bf16(w1[f][:]*s1) AND bias1[f] = w1[f]·t1 ----------------
__global__ __launch_bounds__(256) void k_w1prep(const float* __restrict__ w1,
                                                const float* __restrict__ s1v,
                                                const float* __restrict__ t1v,
                                                unsigned short* __restrict__ w1s,
                                                float* __restrict__ bias1){
    const int f = blockIdx.x, t = threadIdx.x;
    float wv = w1[f * 256 + t];
    w1s[f * 256 + t] = f2bf(wv * s1v[t]);
    float s = wv * t1v[t];
    #pragma unroll
    for (int m = 1; m < 64; m <<= 1) s += __shfl_xor(s, m);
    __shared__ float red[4];
    if ((t & 63) == 0) red[t >> 6] = s;
    __syncthreads();
    if (t == 0) bias1[f] = red[0] + red[1] + red[2] + red[3];
}

// ---------------- K3 v4: dual-stream pipelined FF (cheap gelu, setprio) ----------------
__global__ __launch_bounds__(256, 2) void k_ff_v4(unsigned short* __restrict__ yT,
                                                  const unsigned short* __restrict__ w1s,
                                                  const unsigned short* __restrict__ w2bf,
                                                  const float* __restrict__ bias1,
                                                  const float* __restrict__ s1, const float* __restrict__ t1,
                                                  float* __restrict__ p2){
    const int b = blockIdx.x, t = threadIdx.x;
    const int lane = t & 63, w = t >> 6;
    const int lr = lane & 15, lh = lane >> 4;

    __shared__ __align__(16) unsigned short x1s[96 * 264];
    __shared__ __align__(16) unsigned short ffs[2][96 * 72];

    {
        const short8v* src = (const short8v*)(yT + (size_t)b * YTSZ);
        short8v* dst = (short8v*)x1s;
        for (int idx = t; idx < 3168; idx += 256) dst[idx] = src[idx];
    }
    __syncthreads();

    const int cw = w * 64;
    const int fl = w * 16 + lh * 4;
    f32x4 acc2[4][6];
    #pragma unroll
    for (int ci = 0; ci < 4; ++ci)
    #pragma unroll
    for (int pj = 0; pj < 6; ++pj)
        acc2[ci][pj] = (f32x4){0.f, 0.f, 0.f, 0.f};

    auto g1_kloop = [&](int fc, f32x4 (&acc1)[6]){
        const int fbase = fc * 64 + w * 16;
        float b4[4];
        #pragma unroll
        for (int r = 0; r < 4; ++r) b4[r] = bias1[fbase + lh * 4 + r];
        #pragma unroll
        for (int pj = 0; pj < 6; ++pj){
            acc1[pj][0] = b4[0]; acc1[pj][1] = b4[1];
            acc1[pj][2] = b4[2]; acc1[pj][3] = b4[3];
        }
        __builtin_amdgcn_s_setprio(1);
        #pragma unroll
        for (int ks = 0; ks < 8; ++ks){
            const int k0 = ks * 32 + lh * 8;
            short8v a0 = *(const short8v*)(w1s + (size_t)(fbase + lr) * 256 + k0);
            #pragma unroll
            for (int pj = 0; pj < 6; ++pj){
                short8v bb = *(const short8v*)(x1s + (pj * 16 + lr) * 264 + k0);
                acc1[pj] = __builtin_amdgcn_mfma_f32_16x16x32_bf16(a0, bb, acc1[pj], 0, 0, 0);
            }
        }
        __builtin_amdgcn_s_setprio(0);
    };
    auto g2 = [&](int fc, int bf){
        __builtin_amdgcn_s_setprio(1);
        #pragma unroll
        for (int ks2 = 0; ks2 < 2; ++ks2){
            const int k0 = ks2 * 32 + lh * 8;
            short8v a2[4];
            #pragma unroll
            for (int ci = 0; ci < 4; ++ci)
                a2[ci] = *(const short8v*)(w2bf + (size_t)(cw + ci * 16 + lr) * 1024 + fc * 64 + k0);
            #pragma unroll
            for (int pj = 0; pj < 6; ++pj){
                short8v bb = *(const short8v*)(ffs[bf] + (pj * 16 + lr) * 72 + k0);
                #pragma unroll
                for (int ci = 0; ci < 4; ++ci)
                    acc2[ci][pj] = __builtin_amdgcn_mfma_f32_16x16x32_bf16(a2[ci], bb, acc2[ci][pj], 0, 0, 0);
            }
        }
        __builtin_amdgcn_s_setprio(0);
    };
    auto gelu_store = [&](const f32x4 (&acc1)[6], int bf){
        #pragma unroll
        for (int pj = 0; pj < 6; ++pj){
            int p = pj * 16 + lr;
            short4v pk;
            #pragma unroll
            for (int r = 0; r < 4; ++r)
                pk[r] = (short)f2bf(fast_gelu(acc1[pj][r]));
            *(short4v*)&ffs[bf][p * 72 + fl] = pk;
        }
    };

    {
        f32x4 acc1[6];
        g1_kloop(0, acc1);
        gelu_store(acc1, 0);
    }
    __syncthreads();
    for (int fc = 0; fc < 15; ++fc){
        f32x4 acc1[6];
        g1_kloop(fc + 1, acc1);
        g2(fc, fc & 1);
        gelu_store(acc1, (fc + 1) & 1);
        __syncthreads();
    }
    g2(15, 1);

    float sv[16], tv[16];
    #pragma unroll
    for (int ci = 0; ci < 4; ++ci)
    #pragma unroll
    for (int r = 0; r < 4; ++r){
        int c = cw + ci * 16 + lh * 4 + r;
        sv[ci * 4 + r] = s1[c];
        tv[ci * 4 + r] = t1[c];
    }
    unsigned short* zb = yT + (size_t)b * YTSZ;
    float cs[16], cq[16];
    #pragma unroll
    for (int i = 0; i < 16; ++i){ cs[i] = 0.f; cq[i] = 0.f; }
    #pragma unroll
    for (int ci = 0; ci < 4; ++ci)
    #pragma unroll
    for (int pj = 0; pj < 6; ++pj){
        int p = pj * 16 + lr;
        if (p < 81){
            int c = cw + ci * 16 + lh * 4;
            short4v yv = *(const short4v*)&x1s[p * 264 + c];
            short4v pk;
            #pragma unroll
            for (int r = 0; r < 4; ++r){
                float x1 = fmaf(bf2f((unsigned short)yv[r]), sv[ci * 4 + r], tv[ci * 4 + r]);
                float z = acc2[ci][pj][r] + x1;
                pk[r] = (short)f2bf(z);
                cs[ci * 4 + r] += z;
                cq[ci * 4 + r] += z * z;
            }
            *(short4v*)(zb + p * YTP + c) = pk;
        }
    }
    #pragma unroll
    for (int i = 0; i < 16; ++i){
        cs[i] = wave16_red(cs[i]);
        cq[i] = wave16_red(cq[i]);
    }
    if (lr == 0){
        #pragma unroll
        for (int ci = 0; ci < 4; ++ci)
        #pragma unroll
        for (int r = 0; r < 4; ++r){
            int c = cw + ci * 16 + lh * 4 + r;
            p2[(size_t)c * 2048 + b]         = cs[ci * 4 + r];
            p2[(size_t)(256 + c) * 2048 + b] = cq[ci * 4 + r];
        }
    }
}

// ---------------- BN2 apply from transposed bf16 z -> f32 out ----------------
__global__ __launch_bounds__(256) void k_bnapply_t(const unsigned short* __restrict__ yTz,
                                                   const float* __restrict__ s2, const float* __restrict__ t2,
                                                   float* __restrict__ out){
    const int b = blockIdx.x, t = threadIdx.x;
    __shared__ __align__(16) unsigned short zs[96 * 264];
    __shared__ float s2s[256], t2s[256];
    s2s[t] = s2[t];
    t2s[t] = t2[t];
    {
        const short8v* src = (const short8v*)(yTz + (size_t)b * YTSZ);
        short8v* dst = (short8v*)zs;
        for (int idx = t; idx < 3168; idx += 256) dst[idx] = src[idx];
    }
    __syncthreads();
    float* ob = out + (size_t)b * CHW;
    for (int idx = t; idx < CHW; idx += 256){
        int c = idx / 81, p = idx - c * 81;
        ob[idx] = fmaf(bf2f(zs[p * 264 + c]), s2s[c], t2s[c]);
    }
}

extern "C" void kernel_launch(void* const* d_in, const int* in_sizes, int n_in,
                              void* d_out, int out_size, void* d_ws, size_t ws_size,
                              hipStream_t stream){
    const float* x     = (const float*)d_in[0];
    const float* qkvw  = (const float*)d_in[1];
    const float* relw1 = (const float*)d_in[2];
    const float* relw2 = (const float*)d_in[3];
    const float* ow    = (const float*)d_in[4];
    const float* ffw1  = (const float*)d_in[5];
    const float* ffw2  = (const float*)d_in[6];
    const float* g1    = (const float*)d_in[7];
    const float* b1    = (const float*)d_in[8];
    const float* g2    = (const float*)d_in[9];
    const float* b2    = (const float*)d_in[10];
    float* out = (float*)d_out;
    char* ws = (char*)d_ws;

    unsigned short* w1rel = (unsigned short*)ws;             // 1,327,104 B
    float* h     = (float*)(ws + 1327104);                   // 262,144 B
    unsigned short* w2bf  = (unsigned short*)(ws + 2117632); // 524,288 B
    unsigned short* qkvwb = (unsigned short*)(ws + 2641920); // 49,152 B
    unsigned short* owb   = (unsigned short*)(ws + 2691072); // 131,072 B
    unsigned short* w1s   = (unsigned short*)(ws + 2822144); // 524,288 B
    float* bias1 = (float*)(ws + 3346432);                   // 4,096 B
    float* s1    = (float*)(ws + 3350528);
    float* t1    = (float*)(ws + 3351552);
    float* s2    = (float*)(ws + 3352576);
    float* t2    = (float*)(ws + 3353600);
    float* p1    = (float*)(ws + 3354624);                   // 4,194,304 B
    float* p2    = (float*)(ws + 7548928);                   // 4,194,304 B
    unsigned short* yT = (unsigned short*)(ws + 11743232);   // 103,809,024 B
    float* p_h = p1;

    hipLaunchKernelGGL(k_prep, dim3(1024), dim3(256), 0, stream,
                       relw1, ffw2, qkvw, ow, w1rel, w2bf, qkvwb, owb);
    hipLaunchKernelGGL(k_h_mfma, dim3(512), dim3(256), 0, stream, x, w1rel, p_h);
    hipLaunchKernelGGL(k_h_red,  dim3(256), dim3(256), 0, stream, p_h, h);
    hipLaunchKernelGGL(k_attn_oproj8, dim3(2048), dim3(512), 0, stream, x, qkvwb, relw2, h, owb, yT, p1);
    hipLaunchKernelGGL(k_red,     dim3(256),  dim3(256), 0, stream, p1, g1, b1, s1, t1);
    hipLaunchKernelGGL(k_w1prep,  dim3(1024), dim3(256), 0, stream, ffw1, s1, t1, w1s, bias1);
    hipLaunchKernelGGL(k_ff_v4,   dim3(2048), dim3(256), 0, stream, yT, w1s, w2bf, bias1, s1, t1, p2);
    hipLaunchKernelGGL(k_red,     dim3(256),  dim3(256), 0, stream, p2, g2, b2, s2, t2);
    hipLaunchKernelGGL(k_bnapply_t, dim3(2048), dim3(256), 0, stream, yT, s2, t2, out);
}